// Round 6
// baseline (193.378 us; speedup 1.0000x reference)
//
#include <hip/hip_runtime.h>
#include <math.h>

#define SEQL 4096
#define L2E 1.44269504088896340736f

#if defined(__has_builtin)
#if __has_builtin(__builtin_amdgcn_exp2f)
#define FAST_EXP2(x) __builtin_amdgcn_exp2f(x)
#endif
#endif
#ifndef FAST_EXP2
#define FAST_EXP2(x) exp2f(x)
#endif

__device__ __forceinline__ float sigmoid_f(float x){ return 1.0f/(1.0f+expf(-x)); }

// ---------------- conv 3x3, pad 1, 64x64 image ------------------------------
template<int CI, int CO, int COG, bool RELU, bool RES>
__global__ __launch_bounds__(256) void conv3x3_k(const float* __restrict__ in,
    const float* __restrict__ wgt, const float* __restrict__ bias,
    const float* __restrict__ res, float* __restrict__ out)
{
  constexpr int CIT = CI/4;
  __shared__ float tin[4][2][6][72];
  __shared__ float red[3][4][COG][66];
  const int tid  = threadIdx.x;
  const int lane = tid & 63;
  const int ty   = tid >> 6;
  const int tyu  = __builtin_amdgcn_readfirstlane(ty);
  const int h0   = blockIdx.x * 4;
  const int co0  = blockIdx.y * COG;
  const int b    = blockIdx.z;

  if (lane < 24){
    int cl = lane / 12, rem = lane % 12, r = rem >> 1, side = rem & 1;
    tin[ty][cl][r][side ? 68 : 3] = 0.0f;
  }

  float acc[4][COG];
  #pragma unroll
  for (int rr=0;rr<4;++rr)
    #pragma unroll
    for (int u=0;u<COG;++u) acc[rr][u] = 0.0f;

  const int ci0 = tyu*CIT;
  for (int cig = ci0; cig < ci0 + CIT; cig += 2){
    #pragma unroll
    for (int k=0;k<3;++k){
      int idx4 = lane + (k<<6);
      int row  = idx4 >> 4;
      int cl = row/6, r = row - cl*6;
      int w4 = (idx4 & 15) << 2;
      int h  = h0 - 1 + r;
      float4 v = make_float4(0.f,0.f,0.f,0.f);
      if (h>=0 && h<64)
        v = *(const float4*)(in + ((size_t)(b*CI+cig+cl)*64 + h)*64 + w4);
      *(float4*)&tin[ty][cl][r][4+w4] = v;
    }
    #pragma unroll
    for (int cl=0; cl<2; ++cl){
      float rv[6][3];
      #pragma unroll
      for (int r=0;r<6;++r)
        #pragma unroll
        for (int c=0;c<3;++c)
          rv[r][c] = tin[ty][cl][r][3+lane+c];
      #pragma unroll
      for (int u=0;u<COG;++u){
        const float* wp = wgt + ((size_t)(co0+u)*CI + cig + cl)*9;
        #pragma unroll
        for (int rr=0;rr<4;++rr)
          #pragma unroll
          for (int j=0;j<3;++j){
            acc[rr][u] = fmaf(rv[rr+j][0], wp[3*j+0], acc[rr][u]);
            acc[rr][u] = fmaf(rv[rr+j][1], wp[3*j+1], acc[rr][u]);
            acc[rr][u] = fmaf(rv[rr+j][2], wp[3*j+2], acc[rr][u]);
          }
      }
    }
  }
  if (ty > 0){
    #pragma unroll
    for (int rr=0;rr<4;++rr)
      #pragma unroll
      for (int u=0;u<COG;++u) red[ty-1][rr][u][lane] = acc[rr][u];
  }
  __syncthreads();
  if (ty == 0){
    #pragma unroll
    for (int rr=0;rr<4;++rr)
      #pragma unroll
      for (int u=0;u<COG;++u){
        float s = acc[rr][u] + red[0][rr][u][lane] + red[1][rr][u][lane]
                + red[2][rr][u][lane] + bias[co0+u];
        size_t ob = ((size_t)(b*CO+co0+u)*64 + h0+rr)*64 + lane;
        if constexpr (RES)  s += res[ob];
        if constexpr (RELU) s = fmaxf(s, 0.0f);
        out[ob] = s;
      }
  }
}

// ---- fused mamba front + scan pass 1 (64-token tiles, 1024-thread blocks).
//      (R5 known-good: uniform weight s_loads, transposed scan LDS, coalesced
//      cA/cH [bd][chunk][n].)
__global__ __launch_bounds__(1024, 4) void mamba_in_k(const float* __restrict__ x2,
    const float* __restrict__ g, const float* __restrict__ be,
    const float* __restrict__ Wip, const float* __restrict__ cw,
    const float* __restrict__ cb, const float* __restrict__ Wxp,
    const float* __restrict__ Wdt, const float* __restrict__ bdt,
    const float* __restrict__ A_log,
    float* __restrict__ xm2, float* __restrict__ szb, float* __restrict__ dlt,
    float* __restrict__ Bm, float* __restrict__ Cm,
    float* __restrict__ cA, float* __restrict__ cH)
{
  __shared__ __align__(16) float xn[68][37];   // LN'd tokens; later aliased xbT[32][68]
  __shared__ __align__(16) float xm[64][68];   // in_proj xm half [d][t]; later dl[d][tok]
  __shared__ __align__(16) float xtT[64][68];  // silu(conv) TRANSPOSED [d][tok]
  __shared__ __align__(16) float xd[64][67];   // x_dbl [tok][j]
  float (*xbT)[68] = reinterpret_cast<float(*)[68]>(&xn[0][0]); // B [n][tok], aliases xn
  const int tid = threadIdx.x, lane = tid & 63, ty = tid >> 6;  // ty 0..15
  const int tyu = __builtin_amdgcn_readfirstlane(ty);
  const int bi = blockIdx.x >> 6;
  const int l0 = (blockIdx.x & 63) << 6;

  // ---- LayerNorm: 67 rows (64 + 3 halo), 8 lanes/row, shfl-tree reduce ----
  {
    const int row = tid >> 3, sub = tid & 7;
    if (row < 67){
      const int tok = l0 - 3 + row;
      const int c0 = sub << 2;
      if (tok >= 0){
        float4 f = *(const float4*)(x2 + (size_t)bi*131072 + (size_t)tok*32 + c0);
        float s = (f.x+f.y)+(f.z+f.w);
        s += __shfl_xor(s,1); s += __shfl_xor(s,2); s += __shfl_xor(s,4);
        const float mu = s * 0.03125f;
        float dx=f.x-mu, dy=f.y-mu, dz=f.z-mu, dw=f.w-mu;
        float q = (dx*dx+dy*dy)+(dz*dz+dw*dw);
        q += __shfl_xor(q,1); q += __shfl_xor(q,2); q += __shfl_xor(q,4);
        const float rstd = 1.0f/sqrtf(q*0.03125f + 1e-5f);
        float4 gv = *(const float4*)(g  + c0);
        float4 bv = *(const float4*)(be + c0);
        xn[row][c0+0] = dx*rstd*gv.x + bv.x;
        xn[row][c0+1] = dy*rstd*gv.y + bv.y;
        xn[row][c0+2] = dz*rstd*gv.z + bv.z;
        xn[row][c0+3] = dw*rstd*gv.w + bv.w;
      } else {
        xn[row][c0+0]=0.0f; xn[row][c0+1]=0.0f;
        xn[row][c0+2]=0.0f; xn[row][c0+3]=0.0f;
      }
    }
  }
  __syncthreads();

  // ---- in_proj ----
  if (ty < 8){
    const int d0 = tyu*8;
    float xvA[32];
    #pragma unroll
    for (int c=0;c<32;++c) xvA[c] = xn[lane][c];
    #pragma unroll
    for (int jj=0;jj<8;++jj){
      const float4* wr = (const float4*)(Wip + (d0+jj)*32);
      float a = 0.0f;
      #pragma unroll
      for (int c4=0;c4<8;++c4){
        float4 w = wr[c4];
        a = fmaf(xvA[c4*4+0], w.x, a);
        a = fmaf(xvA[c4*4+1], w.y, a);
        a = fmaf(xvA[c4*4+2], w.z, a);
        a = fmaf(xvA[c4*4+3], w.w, a);
      }
      xm[d0+jj][lane] = a;
    }
    if (lane < 3){
      float xvB[32];
      #pragma unroll
      for (int c=0;c<32;++c) xvB[c] = xn[64+lane][c];
      #pragma unroll
      for (int jj=0;jj<8;++jj){
        const float4* wr = (const float4*)(Wip + (d0+jj)*32);
        float a = 0.0f;
        #pragma unroll
        for (int c4=0;c4<8;++c4){
          float4 w = wr[c4];
          a = fmaf(xvB[c4*4+0], w.x, a);
          a = fmaf(xvB[c4*4+1], w.y, a);
          a = fmaf(xvB[c4*4+2], w.z, a);
          a = fmaf(xvB[c4*4+3], w.w, a);
        }
        xm[d0+jj][64+lane] = a;
      }
    }
  } else {
    const int d0z = (tyu-8)*8;
    float xvC[32];
    #pragma unroll
    for (int c=0;c<32;++c) xvC[c] = xn[lane+3][c];
    #pragma unroll
    for (int jj=0;jj<8;++jj){
      const float4* wr = (const float4*)(Wip + (64+d0z+jj)*32);
      float a = 0.0f;
      #pragma unroll
      for (int c4=0;c4<8;++c4){
        float4 w = wr[c4];
        a = fmaf(xvC[c4*4+0], w.x, a);
        a = fmaf(xvC[c4*4+1], w.y, a);
        a = fmaf(xvC[c4*4+2], w.z, a);
        a = fmaf(xvC[c4*4+3], w.w, a);
      }
      szb[((size_t)(bi*64+d0z+jj))*SEQL + l0 + lane] = a * sigmoid_f(a);
    }
  }
  __syncthreads();

  // ---- depthwise conv1d (4 taps) + silu ----
  #pragma unroll
  for (int jj=0;jj<4;++jj){
    int d = tyu*4 + jj;
    float4 w = *(const float4*)(cw + d*4);
    float a = xm[d][lane]*w.x + xm[d][lane+1]*w.y
            + xm[d][lane+2]*w.z + xm[d][lane+3]*w.w + cb[d];
    float s = a * sigmoid_f(a);
    xtT[d][lane] = s;
    xm2[((size_t)(bi*64+d))*SEQL + l0 + lane] = s;
  }
  __syncthreads();

  // ---- x_proj ----
  {
    float xv[64];
    #pragma unroll
    for (int c=0;c<64;++c) xv[c] = xtT[c][lane];
    for (int j=tyu; j<66; j+=16){
      const float4* wr = (const float4*)(Wxp + j*64);
      float a = 0.0f;
      #pragma unroll
      for (int c4=0;c4<16;++c4){
        float4 w = wr[c4];
        a = fmaf(xv[c4*4+0], w.x, a);
        a = fmaf(xv[c4*4+1], w.y, a);
        a = fmaf(xv[c4*4+2], w.z, a);
        a = fmaf(xv[c4*4+3], w.w, a);
      }
      xd[lane][j] = a;
    }
  }
  __syncthreads();

  // ---- dt_proj + softplus, B/C permuted store, xbT copy ----
  {
    float dt0 = xd[lane][0], dt1 = xd[lane][1];
    #pragma unroll
    for (int k=0;k<4;++k){
      int d2 = tyu*4 + k;
      float2 wd = *(const float2*)(Wdt + d2*2);
      float v = dt0*wd.x + dt1*wd.y + bdt[d2];
      float sp = fmaxf(v,0.0f) + log1pf(expf(-fabsf(v)));
      dlt[((size_t)(bi*64+d2))*SEQL + l0 + lane] = sp;
      xm[d2][lane] = sp;                      // dl[d][tok] (aliases xm)
    }
    const int which = tyu >> 3, gq = tyu & 7;
    float* dst = which ? Cm : Bm;
    size_t base = ((size_t)bi*SEQL + l0 + lane)*32 + gq*4;
    const int s2 = 2 + which*32;
    float4 f0;
    f0.x = xd[lane][s2+gq+ 0]; f0.y = xd[lane][s2+gq+ 8];
    f0.z = xd[lane][s2+gq+16]; f0.w = xd[lane][s2+gq+24];
    *(float4*)(dst + base) = f0;
    if (!which){                               // B transposed: xbT[n][tok]
      xbT[gq     ][lane] = f0.x;
      xbT[gq +  8][lane] = f0.y;
      xbT[gq + 16][lane] = f0.z;
      xbT[gq + 24][lane] = f0.w;
    }
  }
  __syncthreads();

  // ---- scan pass 1: ds_read_b128 over t; cA/cH [bd][chunk][n] coalesced ----
  {
    const int d  = tid >> 4;
    const int gg = tid & 15;
    const int chunk = blockIdx.x & 63;
    const int bd = bi*64 + d;
    float Av0 = -expf(A_log[d*32 + gg     ]) * L2E;
    float Av1 = -expf(A_log[d*32 + gg + 16]) * L2E;
    float h0=0.0f, h1=0.0f, aP0=1.0f, aP1=1.0f;
    #pragma unroll 2
    for (int t0=0;t0<64;t0+=4){
      float4 dl4 = *(const float4*)&xm [d    ][t0];
      float4 xs4 = *(const float4*)&xtT[d    ][t0];
      float4 b04 = *(const float4*)&xbT[gg   ][t0];
      float4 b14 = *(const float4*)&xbT[gg+16][t0];
      #pragma unroll
      for (int k=0;k<4;++k){
        float dlv = (k==0)? dl4.x : (k==1)? dl4.y : (k==2)? dl4.z : dl4.w;
        float xsv = (k==0)? xs4.x : (k==1)? xs4.y : (k==2)? xs4.z : xs4.w;
        float bv0 = (k==0)? b04.x : (k==1)? b04.y : (k==2)? b04.z : b04.w;
        float bv1 = (k==0)? b14.x : (k==1)? b14.y : (k==2)? b14.z : b14.w;
        float m  = dlv * xsv;
        float a0 = FAST_EXP2(dlv*Av0);
        float a1 = FAST_EXP2(dlv*Av1);
        h0 = fmaf(a0, h0, m*bv0);  aP0 *= a0;
        h1 = fmaf(a1, h1, m*bv1);  aP1 *= a1;
      }
    }
    size_t base = ((size_t)bd*64 + chunk)*32;
    cA[base + gg] = aP0; cA[base + gg + 16] = aP1;
    cH[base + gg] = h0;  cH[base + gg + 16] = h1;
  }
}

// ---- fused scan pass 2 + out_proj. Block = (batch, 64-token chunk), ALL d.
//      Prefix: serial over predecessor chunks from cA/cH (coalesced 128B/step).
//      Recurrence replay: thread (d, gg0..15) x 2 n-chains, operands staged in
//      LDS once (float4 coalesced), y reduced via 4-step shfl, y kept in LDS.
//      Epilogue: out_proj with wave-uniform s_load weights -> ym. yt never
//      exists in global memory; replaces scan_p2 + outproj_k.
__global__ __launch_bounds__(1024, 4) void mamba_out_k(const float* __restrict__ dlt,
    const float* __restrict__ xssm, const float* __restrict__ szb,
    const float* __restrict__ Bm, const float* __restrict__ Cm,
    const float* __restrict__ A_log, const float* __restrict__ Dp,
    const float* __restrict__ cA, const float* __restrict__ cHs,
    const float* __restrict__ Wout, float* __restrict__ ym)
{
  __shared__ __align__(16) float dl32[64][36];  // delta   [d][t]
  __shared__ __align__(16) float xs32[64][36];  // conv-silu x [d][t]
  __shared__ __align__(16) float z32 [64][36];  // silu(z) [d][t]
  __shared__ __align__(16) float B32 [32][36];  // B [n][t]
  __shared__ __align__(16) float ct32[32][34];  // C [t][n]
  __shared__ __align__(16) float ysT [64][68];  // y [d][t] (full 64 tokens)
  const int tid = threadIdx.x, lane = tid & 63, ty = tid >> 6;
  const int tyu = __builtin_amdgcn_readfirstlane(ty);
  const int bi = blockIdx.x >> 6;
  const int chunk = blockIdx.x & 63;
  const int l0 = chunk << 6;

  const int d = tid >> 4, gg = tid & 15;
  const int bd = bi*64 + d;
  const float Av0 = -expf(A_log[d*32 + gg     ]) * L2E;
  const float Av1 = -expf(A_log[d*32 + gg + 16]) * L2E;
  const float Dv  = Dp[d];

  // ---- prefix over chunks 0..chunk-1 (serial recurrence on chunk summaries) ----
  float h0 = 0.0f, h1 = 0.0f;
  {
    const float* pa = cA  + (size_t)bd*64*32;
    const float* ph = cHs + (size_t)bd*64*32;
    #pragma unroll 4
    for (int c = 0; c < chunk; ++c){
      float a0 = pa[c*32 + gg     ], q0 = ph[c*32 + gg     ];
      float a1 = pa[c*32 + gg + 16], q1 = ph[c*32 + gg + 16];
      h0 = fmaf(a0, h0, q0);
      h1 = fmaf(a1, h1, q1);
    }
  }

  // ---- two 32-token subtiles: stage -> replay recurrence -> y to LDS ----
  #pragma unroll
  for (int s = 0; s < 2; ++s){
    const int t0 = s << 5;
    if (tid < 512){
      int dd = tid >> 3, f = (tid & 7) << 2;
      *(float4*)&dl32[dd][f] = *(const float4*)(dlt + (size_t)(bi*64+dd)*SEQL + l0 + t0 + f);
      *(float4*)&z32 [dd][f] = *(const float4*)(szb + (size_t)(bi*64+dd)*SEQL + l0 + t0 + f);
    } else {
      int u = tid - 512;
      int dd = u >> 3, f = (u & 7) << 2;
      *(float4*)&xs32[dd][f] = *(const float4*)(xssm + (size_t)(bi*64+dd)*SEQL + l0 + t0 + f);
      if (u < 256){                      // B: [tok][p] permuted, p=4q+j <-> n=q+8j
        int tok = u >> 3, q = u & 7;
        float4 fb = *(const float4*)(Bm + ((size_t)(bi*SEQL) + l0 + t0 + tok)*32 + q*4);
        B32[q     ][tok] = fb.x;
        B32[q +  8][tok] = fb.y;
        B32[q + 16][tok] = fb.z;
        B32[q + 24][tok] = fb.w;
      } else {
        int v = u - 256;
        int tok = v >> 3, q = v & 7;
        float4 fc = *(const float4*)(Cm + ((size_t)(bi*SEQL) + l0 + t0 + tok)*32 + q*4);
        ct32[tok][q     ] = fc.x;
        ct32[tok][q +  8] = fc.y;
        ct32[tok][q + 16] = fc.z;
        ct32[tok][q + 24] = fc.w;
      }
    }
    __syncthreads();

    #pragma unroll 4
    for (int t = 0; t < 32; ++t){
      float dlv = dl32[d][t];
      float xsv = xs32[d][t];
      float m   = dlv * xsv;
      float bv0 = B32[gg   ][t];
      float bv1 = B32[gg+16][t];
      float a0 = FAST_EXP2(dlv*Av0);
      float a1 = FAST_EXP2(dlv*Av1);
      h0 = fmaf(a0, h0, m*bv0);
      h1 = fmaf(a1, h1, m*bv1);
      float part = fmaf(h1, ct32[t][gg+16], h0*ct32[t][gg]);
      part += __shfl_xor(part,1); part += __shfl_xor(part,2);
      part += __shfl_xor(part,4); part += __shfl_xor(part,8);
      if (gg == 0)
        ysT[d][t0 + t] = fmaf(xsv, Dv, part) * z32[d][t];
    }
    __syncthreads();
  }

  // ---- out_proj epilogue: wave tyu -> out rows tyu, tyu+16; tokens = lane ----
  {
    const float4* w0 = (const float4*)(Wout + tyu*64);
    const float4* w1 = (const float4*)(Wout + (tyu+16)*64);
    float a0 = 0.0f, a1 = 0.0f;
    #pragma unroll
    for (int c4 = 0; c4 < 16; ++c4){
      float4 wa = w0[c4], wb = w1[c4];
      float y0 = ysT[c4*4+0][lane];
      float y1 = ysT[c4*4+1][lane];
      float y2 = ysT[c4*4+2][lane];
      float y3 = ysT[c4*4+3][lane];
      a0 = fmaf(y3, wa.w, fmaf(y2, wa.z, fmaf(y1, wa.y, fmaf(y0, wa.x, a0))));
      a1 = fmaf(y3, wb.w, fmaf(y2, wb.z, fmaf(y1, wb.y, fmaf(y0, wb.x, a1))));
    }
    ym[(size_t)(bi*32 + tyu     )*SEQL + l0 + lane] = a0;
    ym[(size_t)(bi*32 + tyu + 16)*SEQL + l0 + lane] = a1;
  }
}

extern "C" void kernel_launch(void* const* d_in, const int* in_sizes, int n_in,
                              void* d_out, int out_size, void* d_ws, size_t ws_size,
                              hipStream_t stream) {
  const float* x        = (const float*)d_in[0];
  const float* conv1_w  = (const float*)d_in[1];
  const float* conv1_b  = (const float*)d_in[2];
  const float* conv2_w  = (const float*)d_in[3];
  const float* conv2_b  = (const float*)d_in[4];
  const float* ln_g     = (const float*)d_in[5];
  const float* ln_b     = (const float*)d_in[6];
  const float* in_proj_w= (const float*)d_in[7];
  const float* conv1d_w = (const float*)d_in[8];
  const float* conv1d_b = (const float*)d_in[9];
  const float* x_proj_w = (const float*)d_in[10];
  const float* dt_proj_w= (const float*)d_in[11];
  const float* dt_proj_b= (const float*)d_in[12];
  const float* A_log    = (const float*)d_in[13];
  const float* Dp       = (const float*)d_in[14];
  const float* out_proj_w=(const float*)d_in[15];
  const float* smooth_w = (const float*)d_in[16];
  const float* smooth_b = (const float*)d_in[17];
  float* out = (float*)d_out;

  float* ws = (float*)d_ws;
  float* t      = ws;                 // (4,64,64,64)  1048576  (free after conv2)
  float* x2     = t      + 1048576;   // (4,32,4096)    524288
  float* xm2    = x2     + 524288;    // (4,64,4096)   1048576
  float* szb    = xm2    + 1048576;   // (4,64,4096)   1048576
  float* dlt    = szb    + 1048576;   // (4,64,4096)   1048576
  float* Bmat   = dlt    + 1048576;   // (4,4096,32)    524288
  float* Cmat   = Bmat   + 524288;    // (4,4096,32)    524288
  float* ym     = Cmat   + 524288;    // (4,32,4096)    524288
  float* cA     = t;                  // (256,64,32)    524288 (aliases t)
  float* cH     = t + 524288;         // (256,64,32)    524288 (aliases t)

  conv3x3_k<32,64,4,true ,false><<<dim3(16,16,4), 256, 0, stream>>>(x,  conv1_w, conv1_b, nullptr, t);
  conv3x3_k<64,32,4,false,true ><<<dim3(16,8,4), 256, 0, stream>>>(t,  conv2_w, conv2_b, x,       x2);
  mamba_in_k  <<<256, 1024, 0, stream>>>(x2, ln_g, ln_b, in_proj_w, conv1d_w, conv1d_b,
                                         x_proj_w, dt_proj_w, dt_proj_b, A_log,
                                         xm2, szb, dlt, Bmat, Cmat, cA, cH);
  mamba_out_k <<<256, 1024, 0, stream>>>(dlt, xm2, szb, Bmat, Cmat, A_log, Dp,
                                         cA, cH, out_proj_w, ym);
  conv3x3_k<32,32,4,false,false><<<dim3(16,8,4), 256, 0, stream>>>(ym, smooth_w, smooth_b, nullptr, out);
}